// Round 5
// baseline (244.011 us; speedup 1.0000x reference)
//
#include <hip/hip_runtime.h>
#include <cstdint>
#include <cstddef>

#define D_     256
#define TWO_D  512
#define R_     16
#define N0_    8192
#define L_     6
#define NL_    8192
#define B_     512
#define TOTAL_ (N0_ + L_*NL_)

#define MT      32          // nodes (M) per block -> 256 blocks
#define XPITCH  520         // bf16 elems per X row (512 + 8 pad)
#define HPITCH  264         // bf16 elems per H row (256 + 8 pad)
#define OPITCH  264         // out-stage pitch (reuses X buffer)
#define NBLK    256         // == CU count; 1 block/CU => co-resident

using short8   = __attribute__((ext_vector_type(8))) short;    // 8 bf16
using f32x4    = __attribute__((ext_vector_type(4))) float;    // 4 fp32 acc
using uint32x4 = __attribute__((ext_vector_type(4))) unsigned; // 16B chunk

__device__ __forceinline__ unsigned short f2bf(float f) {
    union { float f; unsigned u; } v; v.f = f;
    unsigned u = v.u;
    return (unsigned short)((u + 0x7FFFu + ((u >> 16) & 1u)) >> 16);  // RNE
}
__device__ __forceinline__ float bf2f(unsigned short h) {
    union { unsigned u; float f; } v; v.u = ((unsigned)h) << 16;
    return v.f;
}
__device__ __forceinline__ float softplus_f(float x) {
    return fmaxf(x, 0.0f) + log1pf(expf(-fabsf(x)));
}

__device__ __forceinline__ void eval_accum(float x, float pos, float neg, float pw,
                                           float& loss, float& posTot, float& negTot,
                                           float& posOK, float& negOK) {
    float tot = pos + neg;
    if (tot > 0.0f) {
        float tgt = pos / fmaxf(tot, 1e-9f);
        loss += tot * (pw * tgt * softplus_f(-x) + (1.0f - tgt) * softplus_f(x));
        posTot += pos; negTot += neg;
        if (x >= 0.0f) posOK += pos; else negOK += neg;
    }
}

// L3-direct load (round-3-validated): reads the coherence point, bypassing
// (and not polluting) L1/L2. Used ONLY for rows published at the most recent
// barrier — so the barrier needs no acquire-invalidate, and L2 stays warm
// with weights + older rows across the whole kernel.
__device__ __forceinline__ void gload16_sc(uint32x4& d, const void* p) {
    asm volatile("global_load_dwordx4 %0, %1, off sc0 sc1"
                 : "=v"(d) : "v"(p) : "memory");
}
#define WAIT_VM0() do { asm volatile("s_waitcnt vmcnt(0)" ::: "memory"); \
                        __builtin_amdgcn_sched_barrier(0); } while (0)

// Release-only grid barrier: waitcnt+wbL2 publishes this block's stores to
// L3, then relaxed arrive/spin. NO acquire — consumers of fresh data use
// sc0/sc1 loads; everything else is stable (write-once) and cache-safe.
__device__ __forceinline__ void grid_barrier_rel(unsigned* bar, int phase) {
    __syncthreads();
    if (threadIdx.x == 0) {
        __builtin_amdgcn_fence(__ATOMIC_RELEASE, "agent");   // drain + wbL2
        __hip_atomic_fetch_add(&bar[phase], 1u, __ATOMIC_RELAXED,
                               __HIP_MEMORY_SCOPE_AGENT);
        unsigned guard = 0;
        while (__hip_atomic_load(&bar[phase], __ATOMIC_RELAXED,
                                 __HIP_MEMORY_SCOPE_AGENT) < (unsigned)NBLK) {
            __builtin_amdgcn_s_sleep(2);
            if (++guard > (1u << 24)) break;   // safety valve vs. deadlock
        }
    }
    __syncthreads();
}

// ---------------------------------------------------------------- prep ----
__global__ void wimg_k(const float* __restrict__ W1in,
                       const float* __restrict__ W2in,
                       unsigned short* __restrict__ img1,
                       unsigned short* __restrict__ img2,
                       float* __restrict__ accum) {
    if (blockIdx.x == 0 && threadIdx.x < 16) accum[threadIdx.x] = 0.0f;
    int b = blockIdx.x;
    const float* W; unsigned short* img; int KS, rb;
    if (b < R_ * 16) { W = W1in; img = img1; KS = 16; rb = b; }
    else             { W = W2in; img = img2; KS = 8;  rb = b - R_ * 16; }
    int r  = rb / KS;
    int ks = rb - r * KS;
    const float* src = W + (size_t)r * KS * 32 * 256;
    #pragma unroll
    for (int it = 0; it < 4; ++it) {
        int item = it * 256 + threadIdx.x;      // 0..1023 = 4q x 256n
        int q = item >> 8, n = item & 255;
        short8 v;
        #pragma unroll
        for (int j = 0; j < 8; ++j)
            v[j] = (short)f2bf(src[(size_t)(ks * 32 + q * 8 + j) * 256 + n]);
        *(short8*)(img + ((((size_t)r * KS + ks) * 4 + q) * 256 + n) * 8) = v;
    }
}

// ---------------------------------------------------------------- fused ----
// v5 = round-0's PROVEN layer codegen (16-slot distance-8 B-fragment
// streaming pipeline, VGPR<=128) made persistent + layer-cyclic, with:
//  * release-only barriers (no per-layer L2 invalidate -> weight refills are
//    warm-L2 hits, fully hidden by the pipeline; rounds 2-4 paid ~7us/layer
//    of serial L3 latency on distance-0 rematerialized weight loads);
//  * freshly-published rows gathered via sc0/sc1 L3-direct loads;
//  * already-published rows prefetched into registers BEFORE the barrier;
//  * fused per-tile eval from the LDS out-stage; last-layer store skipped.
__global__ __launch_bounds__(512, 2)
void fused_k(unsigned short* __restrict__ storeb,
             const int* __restrict__ thax,
             const float* __restrict__ table,
             const int* __restrict__ par_all,           // [L][NL][2]
             const unsigned short* __restrict__ w1img,  // [R][16][4][256][8]
             const unsigned short* __restrict__ w2img,  // [R][8][4][256][8]
             const float* __restrict__ b1v,
             const float* __restrict__ b2v,
             const float* __restrict__ eval_w,
             const float* __restrict__ eval_b,
             const float* __restrict__ pos_vals,
             const float* __restrict__ neg_vals,
             const float* __restrict__ pos_weight,
             float* __restrict__ accum,
             unsigned* __restrict__ bar,
             float* __restrict__ out) {
    __shared__ unsigned short X[MT * XPITCH];   // 33280 B (also out-stage)
    __shared__ unsigned short H[MT * HPITCH];   // 16896 B
    __shared__ float shred[5];

    const int bid  = blockIdx.x;
    const int tid  = threadIdx.x;
    const int w    = tid >> 6;        // wave 0..7 -> n-slice base w*32
    const int lane = tid & 63;
    const int q    = lane >> 4;
    const int ml   = lane & 15;
    const int nb   = w * 32;
    const int c16c = tid & 31;        // 16B chunk index within a 512B row

    const int r  = (bid & 7) | (((bid >> 3) & 1) << 3);   // XCD-local rule
    const int mt = bid >> 4;
    const int nodeInLayer0 = r * B_ + mt * MT;

    const unsigned short* w1r = w1img + (size_t)r * 16 * 4 * 256 * 8;
    const unsigned short* w2r = w2img + (size_t)r * 8 * 4 * 256 * 8;
    const size_t fb = (size_t)(q * 256 + nb + ml) * 8;   // per-lane frag base

    // --- streaming B-fragment file: 8 logical slots x 2 frags (64 VGPR),
    // distance-8. Cyclic invariant: at every layer entry, slots hold
    // W1 frags 0..7 (prologue establishes it; GEMM2 refills maintain it).
    short8 breg[16];
    #pragma unroll
    for (int p = 0; p < 8; ++p) {
        breg[p * 2 + 0] = *(const short8*)(&w1r[fb + (size_t)p * 8192]);
        breg[p * 2 + 1] = *(const short8*)(&w1r[fb + (size_t)p * 8192 + 128]);
    }

    // layer-invariant scalars
    const float ew0 = eval_w[lane * 4 + 0], ew1 = eval_w[lane * 4 + 1];
    const float ew2 = eval_w[lane * 4 + 2], ew3 = eval_w[lane * 4 + 3];
    const float eb = eval_b[0], pw = pos_weight[0];
    float bias1[2], bias2[2];
    #pragma unroll
    for (int ni = 0; ni < 2; ++ni) {
        bias1[ni] = b1v[r * D_ + nb + ni * 16 + ml];
        bias2[ni] = b2v[r * D_ + nb + ni * 16 + ml];
    }
    float loss = 0.f, posTot = 0.f, negTot = 0.f, posOK = 0.f, negOK = 0.f;

    // parent indices for layer 0 (read-only input, load any time)
    int pidx[4];
    #pragma unroll
    for (int it = 0; it < 4; ++it) {
        int c = it * 512 + tid;
        pidx[it] = par_all[(nodeInLayer0 + (c >> 6)) * 2 + ((c & 63) >> 5)];
    }

    // ---- phase 0: init gather + eval (normal cached stores; published by
    // the release-wbL2 at bar[0]).
    {
        int base = bid * MT;
        #pragma unroll
        for (int rr = 0; rr < 4; ++rr) {
            int row = base + w * 4 + rr;
            int t = thax[row];
            float4 v = *(const float4*)(table + (size_t)t * D_ + lane * 4);
            ushort4 o;
            o.x = f2bf(v.x); o.y = f2bf(v.y); o.z = f2bf(v.z); o.w = f2bf(v.w);
            *(ushort4*)(storeb + (size_t)row * D_ + lane * 4) = o;
            float s = bf2f(o.x)*ew0 + bf2f(o.y)*ew1 + bf2f(o.z)*ew2 + bf2f(o.w)*ew3;
            #pragma unroll
            for (int off = 32; off > 0; off >>= 1) s += __shfl_down(s, off);
            if (lane == 0)
                eval_accum(s + eb, pos_vals[row], neg_vals[row], pw,
                           loss, posTot, negTot, posOK, negOK);
        }
    }
    grid_barrier_rel(bar, 0);

    uint32x4 pf[4];   // gather chunks (prefetched ones live across barriers)

    for (int l = 0; l < L_; ++l) {
        // ---- finish the gather: rows published at the LAST barrier only
        // (everything older was prefetched cached pre-barrier). sc0/sc1
        // L3-direct => correct without any L2 invalidate.
        int prevLimit = (l == 0) ? 0 : (N0_ + (l - 1) * NL_);
        #pragma unroll
        for (int it = 0; it < 4; ++it) {
            if (pidx[it] >= prevLimit)
                gload16_sc(pf[it], (const char*)storeb +
                           ((size_t)(unsigned)pidx[it] << 9) + (c16c << 4));
        }
        WAIT_VM0();
        #pragma unroll
        for (int it = 0; it < 4; ++it) {
            int c = it * 512 + tid;
            int m = c >> 6;
            int j = (c & 63) >> 5;
            *((uint32x4*)(&X[m * XPITCH + j * D_ + c16c * 8])) = pf[it];
        }
        __syncthreads();

        // next-layer parent indices: independent, hides under the GEMMs
        int pidxN[4];
        if (l < L_ - 1) {
            const int* parN = par_all + (size_t)(l + 1) * NL_ * 2;
            #pragma unroll
            for (int it = 0; it < 4; ++it) {
                int c = it * 512 + tid;
                pidxN[it] = parN[(nodeInLayer0 + (c >> 6)) * 2 + ((c & 63) >> 5)];
            }
        }

        // ---- GEMM1: [32x512]@[512x256] -> H, relu(.+b1). Streaming refills:
        // first half pulls W1 ks+8, second half pulls W2 ks-8 (warm L2).
        f32x4 acc[2][2] = {};
        #pragma unroll
        for (int ks = 0; ks < 16; ++ks) {
            int slot = (ks & 7) * 2;
            short8 bb0 = breg[slot + 0];
            short8 bb1 = breg[slot + 1];
            if (ks < 8) {
                breg[slot + 0] = *(const short8*)(&w1r[fb + (size_t)(ks + 8) * 8192]);
                breg[slot + 1] = *(const short8*)(&w1r[fb + (size_t)(ks + 8) * 8192 + 128]);
            } else {
                breg[slot + 0] = *(const short8*)(&w2r[fb + (size_t)(ks - 8) * 8192]);
                breg[slot + 1] = *(const short8*)(&w2r[fb + (size_t)(ks - 8) * 8192 + 128]);
            }
            int k0 = ks * 32 + q * 8;
            short8 a0 = *(const short8*)(&X[ml * XPITCH + k0]);
            short8 a1 = *(const short8*)(&X[(16 + ml) * XPITCH + k0]);
            acc[0][0] = __builtin_amdgcn_mfma_f32_16x16x32_bf16(a0, bb0, acc[0][0], 0, 0, 0);
            acc[1][0] = __builtin_amdgcn_mfma_f32_16x16x32_bf16(a1, bb0, acc[1][0], 0, 0, 0);
            acc[0][1] = __builtin_amdgcn_mfma_f32_16x16x32_bf16(a0, bb1, acc[0][1], 0, 0, 0);
            acc[1][1] = __builtin_amdgcn_mfma_f32_16x16x32_bf16(a1, bb1, acc[1][1], 0, 0, 0);
        }
        #pragma unroll
        for (int ni = 0; ni < 2; ++ni) {
            int n = nb + ni * 16 + ml;
            #pragma unroll
            for (int mi = 0; mi < 2; ++mi)
                #pragma unroll
                for (int v = 0; v < 4; ++v) {
                    int row = mi * 16 + q * 4 + v;   // C/D: row = quad*4+reg
                    float x = acc[mi][ni][v] + bias1[ni];
                    H[row * HPITCH + n] = f2bf(x > 0.0f ? x : 0.0f);
                }
        }
        __syncthreads();

        // ---- GEMM2: [32x256]@[256x256] (+b2). Slots hold W2 0..7; refills
        // pull NEXT layer's W1 0..7 (weights are layer-invariant).
        f32x4 acc2[2][2] = {};
        #pragma unroll
        for (int ks = 0; ks < 8; ++ks) {
            int slot = ks * 2;
            short8 bb0 = breg[slot + 0];
            short8 bb1 = breg[slot + 1];
            if (l != L_ - 1) {
                breg[slot + 0] = *(const short8*)(&w1r[fb + (size_t)ks * 8192]);
                breg[slot + 1] = *(const short8*)(&w1r[fb + (size_t)ks * 8192 + 128]);
            }
            int k0 = ks * 32 + q * 8;
            short8 a0 = *(const short8*)(&H[ml * HPITCH + k0]);
            short8 a1 = *(const short8*)(&H[(16 + ml) * HPITCH + k0]);
            acc2[0][0] = __builtin_amdgcn_mfma_f32_16x16x32_bf16(a0, bb0, acc2[0][0], 0, 0, 0);
            acc2[1][0] = __builtin_amdgcn_mfma_f32_16x16x32_bf16(a1, bb0, acc2[1][0], 0, 0, 0);
            acc2[0][1] = __builtin_amdgcn_mfma_f32_16x16x32_bf16(a0, bb1, acc2[0][1], 0, 0, 0);
            acc2[1][1] = __builtin_amdgcn_mfma_f32_16x16x32_bf16(a1, bb1, acc2[1][1], 0, 0, 0);
        }
        // X reads all finished before post-GEMM1 barrier -> reuse X as out-stage
        #pragma unroll
        for (int ni = 0; ni < 2; ++ni) {
            int n = nb + ni * 16 + ml;
            #pragma unroll
            for (int mi = 0; mi < 2; ++mi)
                #pragma unroll
                for (int v = 0; v < 4; ++v) {
                    int row = mi * 16 + q * 4 + v;
                    float x = acc2[mi][ni][v] + bias2[ni];
                    X[row * OPITCH + n] = f2bf(x);
                }
        }
        __syncthreads();

        size_t outBase = (size_t)(N0_ + l * NL_ + nodeInLayer0);
        // coalesced cached store (skip last layer: nobody gathers from it);
        // published to L3 by this barrier's release-wbL2.
        if (l != L_ - 1) {
            #pragma unroll
            for (int it = 0; it < 2; ++it) {
                int c   = it * 512 + tid;       // 0..1023 = 32 rows x 32 chunks
                int m   = c >> 5;
                int cc  = c & 31;
                uint4 v = *((const uint4*)(&X[m * OPITCH]) + cc);
                *((uint4*)(storeb + (outBase + m) * D_) + cc) = v;
            }
        }
        // fused eval of this tile from the LDS out-stage
        #pragma unroll
        for (int rr = 0; rr < 4; ++rr) {
            int row = w * 4 + rr;
            ushort4 vv = *(const ushort4*)(&X[row * OPITCH + lane * 4]);
            float s = bf2f(vv.x)*ew0 + bf2f(vv.y)*ew1 + bf2f(vv.z)*ew2 + bf2f(vv.w)*ew3;
            #pragma unroll
            for (int off = 32; off > 0; off >>= 1) s += __shfl_down(s, off);
            if (lane == 0)
                eval_accum(s + eb, pos_vals[outBase + row], neg_vals[outBase + row], pw,
                           loss, posTot, negTot, posOK, negOK);
        }
        if (l < L_ - 1) {
            // prefetch for layer l+1: rows < N0+l*NL were published >= one
            // barrier ago -> cached loads are safe and (largely) L2-warm.
            int limit = N0_ + l * NL_;
            #pragma unroll
            for (int it = 0; it < 4; ++it) {
                if (pidxN[it] < limit)
                    pf[it] = *((const uint32x4*)((const char*)storeb +
                              ((size_t)(unsigned)pidxN[it] << 9) + (c16c << 4)));
            }
            grid_barrier_rel(bar, 1 + l);   // phases 1..5
            #pragma unroll
            for (int it = 0; it < 4; ++it) pidx[it] = pidxN[it];
        }
    }

    // ---- final reduce: block-local via LDS, one device-atomic set per block
    if (tid < 5) shred[tid] = 0.0f;
    __syncthreads();
    if (lane == 0) {
        atomicAdd(&shred[0], loss);
        atomicAdd(&shred[1], posTot);
        atomicAdd(&shred[2], negTot);
        atomicAdd(&shred[3], posOK);
        atomicAdd(&shred[4], negOK);
    }
    __syncthreads();
    if (tid < 5) atomicAdd(&accum[tid], shred[tid]);   // device-scope, at L3
    __syncthreads();
    if (tid == 0) {
        __builtin_amdgcn_fence(__ATOMIC_RELEASE, "agent");
        __hip_atomic_fetch_add(&bar[6], 1u, __ATOMIC_RELAXED,
                               __HIP_MEMORY_SCOPE_AGENT);
        if (bid == 0) {
            unsigned guard = 0;
            while (__hip_atomic_load(&bar[6], __ATOMIC_RELAXED,
                                     __HIP_MEMORY_SCOPE_AGENT) < (unsigned)NBLK) {
                __builtin_amdgcn_s_sleep(2);
                if (++guard > (1u << 24)) break;
            }
            __builtin_amdgcn_fence(__ATOMIC_ACQUIRE, "agent");
            float vloss   = __hip_atomic_load(&accum[0], __ATOMIC_RELAXED, __HIP_MEMORY_SCOPE_AGENT);
            float vposTot = __hip_atomic_load(&accum[1], __ATOMIC_RELAXED, __HIP_MEMORY_SCOPE_AGENT);
            float vnegTot = __hip_atomic_load(&accum[2], __ATOMIC_RELAXED, __HIP_MEMORY_SCOPE_AGENT);
            float vposOK  = __hip_atomic_load(&accum[3], __ATOMIC_RELAXED, __HIP_MEMORY_SCOPE_AGENT);
            float vnegOK  = __hip_atomic_load(&accum[4], __ATOMIC_RELAXED, __HIP_MEMORY_SCOPE_AGENT);
            out[0] = vloss;
            out[1] = (vposTot > 0.0f) ? vposOK / fmaxf(vposTot, 1e-9f) : 1.0f;
            out[2] = (vnegTot > 0.0f) ? vnegOK / fmaxf(vnegTot, 1e-9f) : 1.0f;
        }
    }
}

// ---------------------------------------------------------------- launch ---
extern "C" void kernel_launch(void* const* d_in, const int* in_sizes, int n_in,
                              void* d_out, int out_size, void* d_ws, size_t ws_size,
                              hipStream_t stream) {
    const int*   thax       = (const int*)  d_in[0];
    const int*   par        = (const int*)  d_in[1];
    const float* pos_vals   = (const float*)d_in[2];
    const float* neg_vals   = (const float*)d_in[3];
    const float* init_table = (const float*)d_in[4];
    const float* W1         = (const float*)d_in[5];
    const float* b1         = (const float*)d_in[6];
    const float* W2         = (const float*)d_in[7];
    const float* b2         = (const float*)d_in[8];
    const float* eval_w     = (const float*)d_in[9];
    const float* eval_b     = (const float*)d_in[10];
    const float* pos_weight = (const float*)d_in[11];
    float* out = (float*)d_out;

    char* ws = (char*)d_ws;
    unsigned short* w1img  = (unsigned short*)(ws);                            // 4 MB
    unsigned short* w2img  = (unsigned short*)(ws + (size_t)4  * 1024 * 1024); // 2 MB
    unsigned short* storeb = (unsigned short*)(ws + (size_t)6  * 1024 * 1024); // 28 MB
    float*          accum  = (float*)(ws + (size_t)6 * 1024 * 1024 +
                                      (size_t)TOTAL_ * D_ * 2);
    unsigned*       bar    = (unsigned*)(accum + 8);   // 8 barrier counters

    hipLaunchKernelGGL(wimg_k, dim3(R_ * 16 + R_ * 8), dim3(256), 0, stream,
                       W1, W2, w1img, w2img, accum);
    hipLaunchKernelGGL(fused_k, dim3(NBLK), dim3(512), 0, stream,
                       storeb, thax, init_table, par, w1img, w2img, b1, b2,
                       eval_w, eval_b, pos_vals, neg_vals, pos_weight,
                       accum, bar, out);
}

// Round 6
// 174.609 us; speedup vs baseline: 1.3975x; 1.3975x over previous
//
#include <hip/hip_runtime.h>
#include <cstdint>
#include <cstddef>

#define D_     256
#define TWO_D  512
#define R_     16
#define N0_    8192
#define L_     6
#define NL_    8192
#define B_     512
#define TOTAL_ (N0_ + L_*NL_)

#define MT      32          // nodes (M) per layer block -> 256 blocks
#define XPITCH  520         // bf16 elems per X row (512 + 8 pad)
#define HPITCH  264         // bf16 elems per H row (256 + 8 pad)
#define OPITCH  264         // out-stage pitch (reuses X buffer)

using short8 = __attribute__((ext_vector_type(8))) short;   // 8 bf16 (4 VGPRs)
using f32x4  = __attribute__((ext_vector_type(4))) float;   // 4 fp32 acc

__device__ __forceinline__ unsigned short f2bf(float f) {
    union { float f; unsigned u; } v; v.f = f;
    unsigned u = v.u;
    return (unsigned short)((u + 0x7FFFu + ((u >> 16) & 1u)) >> 16);  // RNE
}
__device__ __forceinline__ float bf2f(unsigned short h) {
    union { unsigned u; float f; } v; v.u = ((unsigned)h) << 16;
    return v.f;
}
__device__ __forceinline__ float softplus_f(float x) {
    return fmaxf(x, 0.0f) + log1pf(expf(-fabsf(x)));
}

__device__ __forceinline__ void eval_accum(float x, float pos, float neg, float pw,
                                           float& loss, float& posTot, float& negTot,
                                           float& posOK, float& negOK) {
    float tot = pos + neg;
    if (tot > 0.0f) {
        float tgt = pos / fmaxf(tot, 1e-9f);
        loss += tot * (pw * tgt * softplus_f(-x) + (1.0f - tgt) * softplus_f(x));
        posTot += pos; negTot += neg;
        if (x >= 0.0f) posOK += pos; else negOK += neg;
    }
}

// ---------------------------------------------------------------- prep ----
// One dispatch doing: (a) W1/W2 fp32 -> bf16 fragment images (blocks 0..191,
// 512 threads cover two of the old 256-thread wimg blocks each), (b) init
// gather + fused init-node eval (blocks 192..447: 32 rows each, one row per
// wave iteration). Init eval partials go to part[block][5] — no atomics, no
// zero-ordering hazard. accum[0..15] zeroed here (block 0), consumed by the
// layer kernels' eval atomics (stream-ordered after prep).
__global__ __launch_bounds__(512)
void prep_k(const float* __restrict__ W1in,
            const float* __restrict__ W2in,
            unsigned short* __restrict__ img1,
            unsigned short* __restrict__ img2,
            const int* __restrict__ thax,
            const float* __restrict__ table,
            unsigned short* __restrict__ storeb,
            const float* __restrict__ eval_w,
            const float* __restrict__ eval_b,
            const float* __restrict__ pos_vals,
            const float* __restrict__ neg_vals,
            const float* __restrict__ pos_weight,
            float* __restrict__ accum,
            float* __restrict__ part) {
    __shared__ float shred[5];
    const int nb  = blockIdx.x;
    const int tid = threadIdx.x;
    if (nb == 0 && tid < 16) accum[tid] = 0.0f;

    if (nb < 192) {
        // ---- weight image build (exact old wimg_k inner loop) ----
        int ob = nb * 2 + (tid >> 8);     // old 256-thread block id, 0..383
        int t  = tid & 255;
        const float* W; unsigned short* img; int KS, r, ks;
        if (ob < R_ * 16) { W = W1in; img = img1; KS = 16; r = ob >> 4; ks = ob & 15; }
        else { W = W2in; img = img2; KS = 8; int rb = ob - R_ * 16; r = rb >> 3; ks = rb & 7; }
        const float* src = W + (size_t)r * KS * 32 * 256;
        #pragma unroll
        for (int it = 0; it < 4; ++it) {
            int item = it * 256 + t;      // 0..1023 = 4q x 256n
            int q = item >> 8, n = item & 255;
            short8 v;
            #pragma unroll
            for (int j = 0; j < 8; ++j)
                v[j] = (short)f2bf(src[(size_t)(ks * 32 + q * 8 + j) * 256 + n]);
            *(short8*)(img + ((((size_t)r * KS + ks) * 4 + q) * 256 + n) * 8) = v;
        }
    } else {
        // ---- init gather + eval: 32 rows per block ----
        int i    = nb - 192;              // 0..255
        int w    = tid >> 6;
        int lane = tid & 63;
        const float ew0 = eval_w[lane * 4 + 0], ew1 = eval_w[lane * 4 + 1];
        const float ew2 = eval_w[lane * 4 + 2], ew3 = eval_w[lane * 4 + 3];
        const float eb = eval_b[0], pw = pos_weight[0];
        float loss = 0.f, posTot = 0.f, negTot = 0.f, posOK = 0.f, negOK = 0.f;
        int base = i * MT;
        #pragma unroll
        for (int rr = 0; rr < 4; ++rr) {
            int row = base + w * 4 + rr;
            int t = thax[row];
            float4 v = *(const float4*)(table + (size_t)t * D_ + lane * 4);
            ushort4 o;
            o.x = f2bf(v.x); o.y = f2bf(v.y); o.z = f2bf(v.z); o.w = f2bf(v.w);
            *(ushort4*)(storeb + (size_t)row * D_ + lane * 4) = o;
            float s = bf2f(o.x)*ew0 + bf2f(o.y)*ew1 + bf2f(o.z)*ew2 + bf2f(o.w)*ew3;
            #pragma unroll
            for (int off = 32; off > 0; off >>= 1) s += __shfl_down(s, off);
            if (lane == 0)
                eval_accum(s + eb, pos_vals[row], neg_vals[row], pw,
                           loss, posTot, negTot, posOK, negOK);
        }
        if (tid < 5) shred[tid] = 0.0f;
        __syncthreads();
        if (lane == 0) {
            atomicAdd(&shred[0], loss);  atomicAdd(&shred[1], posTot);
            atomicAdd(&shred[2], negTot); atomicAdd(&shred[3], posOK);
            atomicAdd(&shred[4], negOK);
        }
        __syncthreads();
        if (tid < 5) part[i * 5 + tid] = shred[tid];
    }
}

// ---------------------------------------------------------------- layer ----
// 256 blocks x 512 threads — PROVEN round-0 body (16-slot distance-8
// B-fragment streaming; GEMM2's B is already register-resident). Additions:
// fused eval of the tile from the LDS out-stage (replaces eval_k's 29 MB
// re-read), and the dead layer-5 global store is skipped.
__global__ __launch_bounds__(512, 2)
void layer_k(unsigned short* __restrict__ storeb,
             const int* __restrict__ par,               // this layer: [NL][2]
             const unsigned short* __restrict__ w1img,  // [R][16][4][256][8]
             const unsigned short* __restrict__ w2img,  // [R][8][4][256][8]
             const float* __restrict__ b1,
             const float* __restrict__ b2,
             int layer,
             const float* __restrict__ eval_w,
             const float* __restrict__ eval_b,
             const float* __restrict__ pos_vals,
             const float* __restrict__ neg_vals,
             const float* __restrict__ pos_weight,
             float* __restrict__ accum) {
    __shared__ unsigned short X[MT * XPITCH];   // 33280 B (also out-stage)
    __shared__ unsigned short H[MT * HPITCH];   // 16896 B
    __shared__ float shred[5];

    int bid = blockIdx.x;
    int r   = (bid & 7) | (((bid >> 3) & 1) << 3);   // XCD-local rule
    int mt  = bid >> 4;
    int tid = threadIdx.x;
    int nodeInLayer0 = r * B_ + mt * MT;

    int w    = tid >> 6;        // wave 0..7 -> n-slice base w*32
    int lane = tid & 63;
    int q    = lane >> 4;
    int ml   = lane & 15;
    int nb   = w * 32;

    const unsigned short* w1r = w1img + (size_t)r * 16 * 4 * 256 * 8;
    const unsigned short* w2r = w2img + (size_t)r * 8 * 4 * 256 * 8;
    size_t fb = (size_t)(q * 256 + nb + ml) * 8;   // per-lane fragment base

    // --- B-fragment register file: preload W1 ks=0..7 (16 frags, 64 VGPR)
    short8 breg[16];
    #pragma unroll
    for (int p = 0; p < 8; ++p) {
        breg[p * 2 + 0] = *(const short8*)(&w1r[fb + (size_t)p * 8192]);
        breg[p * 2 + 1] = *(const short8*)(&w1r[fb + (size_t)p * 8192 + 128]);
    }

    if (tid < 5) shred[tid] = 0.0f;

    // gather parents -> X: 32 rows x 2 parents x 32 chunks = 2048, 4/thread
    int pidx[4];
    #pragma unroll
    for (int it = 0; it < 4; ++it) {
        int c = it * 512 + tid;
        pidx[it] = par[(nodeInLayer0 + (c >> 6)) * 2 + ((c & 63) >> 5)];
    }
    #pragma unroll
    for (int it = 0; it < 4; ++it) {
        int c   = it * 512 + tid;
        int m   = c >> 6;
        int rem = c & 63;
        int j   = rem >> 5;
        int c16 = rem & 31;
        uint4 v = *((const uint4*)(storeb + (size_t)pidx[it] * D_) + c16);
        *((uint4*)(&X[m * XPITCH + j * D_ + c16 * 8])) = v;
    }
    __syncthreads();

    // ---- GEMM1: [32 x 512] @ [512 x 256] -> H, relu(.+b1) ----
    f32x4 acc[2][2] = {};
    #pragma unroll
    for (int ks = 0; ks < 16; ++ks) {
        int slot = (ks & 7) * 2;
        short8 b0 = breg[slot + 0];
        short8 b1f = breg[slot + 1];
        // refill slot: W1 frag ks+8 during first half, W2 frag ks-8 after
        if (ks < 8) {
            breg[slot + 0] = *(const short8*)(&w1r[fb + (size_t)(ks + 8) * 8192]);
            breg[slot + 1] = *(const short8*)(&w1r[fb + (size_t)(ks + 8) * 8192 + 128]);
        } else {
            breg[slot + 0] = *(const short8*)(&w2r[fb + (size_t)(ks - 8) * 8192]);
            breg[slot + 1] = *(const short8*)(&w2r[fb + (size_t)(ks - 8) * 8192 + 128]);
        }
        int k0 = ks * 32 + q * 8;
        short8 a0 = *(const short8*)(&X[ml * XPITCH + k0]);
        short8 a1 = *(const short8*)(&X[(16 + ml) * XPITCH + k0]);
        acc[0][0] = __builtin_amdgcn_mfma_f32_16x16x32_bf16(a0, b0,  acc[0][0], 0, 0, 0);
        acc[1][0] = __builtin_amdgcn_mfma_f32_16x16x32_bf16(a1, b0,  acc[1][0], 0, 0, 0);
        acc[0][1] = __builtin_amdgcn_mfma_f32_16x16x32_bf16(a0, b1f, acc[0][1], 0, 0, 0);
        acc[1][1] = __builtin_amdgcn_mfma_f32_16x16x32_bf16(a1, b1f, acc[1][1], 0, 0, 0);
    }
    #pragma unroll
    for (int ni = 0; ni < 2; ++ni) {
        int n = nb + ni * 16 + ml;
        float bias = b1[r * D_ + n];
        #pragma unroll
        for (int mi = 0; mi < 2; ++mi)
            #pragma unroll
            for (int v = 0; v < 4; ++v) {
                int row = mi * 16 + q * 4 + v;   // C/D: row = quad*4+reg
                float x = acc[mi][ni][v] + bias;
                H[row * HPITCH + n] = f2bf(x > 0.0f ? x : 0.0f);
            }
    }
    __syncthreads();

    // ---- GEMM2: [32 x 256] @ [256 x 256] (+b2) — B already in registers ----
    f32x4 acc2[2][2] = {};
    #pragma unroll
    for (int ks = 0; ks < 8; ++ks) {
        int slot = ks * 2;
        int k0 = ks * 32 + q * 8;
        short8 a0 = *(const short8*)(&H[ml * HPITCH + k0]);
        short8 a1 = *(const short8*)(&H[(16 + ml) * HPITCH + k0]);
        acc2[0][0] = __builtin_amdgcn_mfma_f32_16x16x32_bf16(a0, breg[slot + 0], acc2[0][0], 0, 0, 0);
        acc2[1][0] = __builtin_amdgcn_mfma_f32_16x16x32_bf16(a1, breg[slot + 0], acc2[1][0], 0, 0, 0);
        acc2[0][1] = __builtin_amdgcn_mfma_f32_16x16x32_bf16(a0, breg[slot + 1], acc2[0][1], 0, 0, 0);
        acc2[1][1] = __builtin_amdgcn_mfma_f32_16x16x32_bf16(a1, breg[slot + 1], acc2[1][1], 0, 0, 0);
    }
    // all X reads finished before post-GEMM1 barrier -> reuse X as out-stage
    #pragma unroll
    for (int ni = 0; ni < 2; ++ni) {
        int n = nb + ni * 16 + ml;
        float bias = b2[r * D_ + n];
        #pragma unroll
        for (int mi = 0; mi < 2; ++mi)
            #pragma unroll
            for (int v = 0; v < 4; ++v) {
                int row = mi * 16 + q * 4 + v;
                float x = acc2[mi][ni][v] + bias;
                X[row * OPITCH + n] = f2bf(x);
            }
    }
    __syncthreads();
    // coalesced store: 32 rows x 512 B (skip for the last layer: nobody
    // gathers from it; eval below reads the LDS out-stage)
    size_t outBase = (size_t)(N0_ + layer * NL_ + nodeInLayer0);
    if (layer != L_ - 1) {
        #pragma unroll
        for (int it = 0; it < 2; ++it) {
            int c   = it * 512 + tid;       // 0..1023 = 32 rows x 32 chunks
            int m   = c >> 5;
            int c16 = c & 31;
            uint4 v = *((const uint4*)(&X[m * OPITCH]) + c16);
            *((uint4*)(storeb + (outBase + m) * D_) + c16) = v;
        }
    }

    // ---- fused eval of this tile from the LDS out-stage (bit-identical
    // bf16 values to what eval_k used to re-read from HBM)
    {
        const float ew0 = eval_w[lane * 4 + 0], ew1 = eval_w[lane * 4 + 1];
        const float ew2 = eval_w[lane * 4 + 2], ew3 = eval_w[lane * 4 + 3];
        const float eb = eval_b[0], pw = pos_weight[0];
        float loss = 0.f, posTot = 0.f, negTot = 0.f, posOK = 0.f, negOK = 0.f;
        #pragma unroll
        for (int rr = 0; rr < 4; ++rr) {
            int row = w * 4 + rr;
            ushort4 vv = *(const ushort4*)(&X[row * OPITCH + lane * 4]);
            float s = bf2f(vv.x)*ew0 + bf2f(vv.y)*ew1 + bf2f(vv.z)*ew2 + bf2f(vv.w)*ew3;
            #pragma unroll
            for (int off = 32; off > 0; off >>= 1) s += __shfl_down(s, off);
            if (lane == 0)
                eval_accum(s + eb, pos_vals[outBase + row], neg_vals[outBase + row], pw,
                           loss, posTot, negTot, posOK, negOK);
        }
        if (lane == 0) {
            atomicAdd(&shred[0], loss);  atomicAdd(&shred[1], posTot);
            atomicAdd(&shred[2], negTot); atomicAdd(&shred[3], posOK);
            atomicAdd(&shred[4], negOK);
        }
        __syncthreads();
        if (tid < 5) atomicAdd(&accum[tid], shred[tid]);
    }
}

// ---------------------------------------------------------------- final ----
__global__ void finalize_k(const float* __restrict__ accum,
                           const float* __restrict__ part,
                           float* __restrict__ out) {
    __shared__ float sh[4][5];
    int tid = threadIdx.x, lane = tid & 63, w = tid >> 6;
    float v[5];
    #pragma unroll
    for (int k = 0; k < 5; ++k) v[k] = part[tid * 5 + k];
    #pragma unroll
    for (int k = 0; k < 5; ++k)
        #pragma unroll
        for (int off = 32; off > 0; off >>= 1) v[k] += __shfl_down(v[k], off);
    if (lane == 0) {
        #pragma unroll
        for (int k = 0; k < 5; ++k) sh[w][k] = v[k];
    }
    __syncthreads();
    if (tid == 0) {
        float t[5];
        #pragma unroll
        for (int k = 0; k < 5; ++k)
            t[k] = accum[k] + sh[0][k] + sh[1][k] + sh[2][k] + sh[3][k];
        out[0] = t[0];
        out[1] = (t[1] > 0.0f) ? t[3] / fmaxf(t[1], 1e-9f) : 1.0f;
        out[2] = (t[2] > 0.0f) ? t[4] / fmaxf(t[2], 1e-9f) : 1.0f;
    }
}

// ---------------------------------------------------------------- launch ---
extern "C" void kernel_launch(void* const* d_in, const int* in_sizes, int n_in,
                              void* d_out, int out_size, void* d_ws, size_t ws_size,
                              hipStream_t stream) {
    const int*   thax       = (const int*)  d_in[0];
    const int*   par        = (const int*)  d_in[1];
    const float* pos_vals   = (const float*)d_in[2];
    const float* neg_vals   = (const float*)d_in[3];
    const float* init_table = (const float*)d_in[4];
    const float* W1         = (const float*)d_in[5];
    const float* b1         = (const float*)d_in[6];
    const float* W2         = (const float*)d_in[7];
    const float* b2         = (const float*)d_in[8];
    const float* eval_w     = (const float*)d_in[9];
    const float* eval_b     = (const float*)d_in[10];
    const float* pos_weight = (const float*)d_in[11];
    float* out = (float*)d_out;

    char* ws = (char*)d_ws;
    unsigned short* w1img  = (unsigned short*)(ws);                            // 4 MB
    unsigned short* w2img  = (unsigned short*)(ws + (size_t)4  * 1024 * 1024); // 2 MB
    unsigned short* storeb = (unsigned short*)(ws + (size_t)6  * 1024 * 1024); // 28 MB
    float*          accum  = (float*)(ws + (size_t)6 * 1024 * 1024 +
                                      (size_t)TOTAL_ * D_ * 2);
    float*          part   = accum + 16;   // 256 x 5 init-eval partials

    hipLaunchKernelGGL(prep_k, dim3(448), dim3(512), 0, stream,
                       W1, W2, w1img, w2img, thax, init_table, storeb,
                       eval_w, eval_b, pos_vals, neg_vals, pos_weight,
                       accum, part);
    for (int l = 0; l < L_; ++l) {
        hipLaunchKernelGGL(layer_k, dim3(256), dim3(512), 0, stream,
                           storeb, par + (size_t)l * NL_ * 2, w1img, w2img, b1, b2, l,
                           eval_w, eval_b, pos_vals, neg_vals, pos_weight, accum);
    }
    hipLaunchKernelGGL(finalize_k, dim3(1), dim3(256), 0, stream,
                       accum, part, out);
}